// Round 2
// baseline (442.805 us; speedup 1.0000x reference)
//
#include <hip/hip_runtime.h>
#include <math.h>

#define N_NODES 50000
#define KNEI    32
#define DIM     128
#define DOUT    128
#define MT      64      // nodes per block
#define KC      64      // K-chunk of the 512-wide cat row
#define AS_STRIDE 68    // padded LDS stride

__global__ __launch_bounds__(512) void sage_fused(
    const float* __restrict__ fea1,
    const float* __restrict__ fea2,
    const int*   __restrict__ idx1,
    const int*   __restrict__ idx2,
    const float* __restrict__ W,
    float*       __restrict__ out)
{
    __shared__ float As[KC][AS_STRIDE];   // A-tile, transposed: As[k][m]
    __shared__ int   idxs[MT][64];        // [node][0:32]=list1, [32:64]=list2

    const int tid = threadIdx.x;
    const int n0  = blockIdx.x * MT;

    // ---- stage neighbor indices for the 64 nodes of this tile ----
    #pragma unroll
    for (int i = 0; i < 4; ++i) {
        int e  = tid + i * 512;           // 0..2047
        int m  = e >> 5;
        int kk = e & 31;
        int node = n0 + m;
        if (node >= N_NODES) node = N_NODES - 1;   // clamp; store is guarded later
        idxs[m][kk]      = idx1[node * KNEI + kk];
        idxs[m][32 + kk] = idx2[node * KNEI + kk];
    }

    float acc[4][4];
    #pragma unroll
    for (int i = 0; i < 4; ++i)
        #pragma unroll
        for (int j = 0; j < 4; ++j) acc[i][j] = 0.f;

    const int j0 = (tid & 31) * 4;        // output column base (0..124)
    const int m0 = (tid >> 5) * 4;        // output row base    (0..60)

    for (int c = 0; c < 8; ++c) {
        // ---------- stage A-tile for this K-chunk ----------
        if (c < 4) {
            // direct features: chunks 0-1 = fea1, 2-3 = fea2
            const float* src = (c < 2) ? fea1 : fea2;
            const int cbase = (c & 1) * 64;
            #pragma unroll
            for (int i = 0; i < 2; ++i) {
                int f  = tid + i * 512;   // 0..1023 float4 slots
                int m  = f >> 4;
                int c4 = (f & 15) * 4;
                int node = n0 + m;
                if (node >= N_NODES) node = N_NODES - 1;
                float4 v = *(const float4*)(src + node * DIM + cbase + c4);
                As[c4 + 0][m] = v.x;
                As[c4 + 1][m] = v.y;
                As[c4 + 2][m] = v.z;
                As[c4 + 3][m] = v.w;
            }
        } else {
            // neighbor-mean chunks: 4-5 = list1, 6-7 = list2
            const int col   = tid & 63;            // column within chunk
            const int kbase = (c & 1) * 64;        // column base within fea1 row
            const int lbase = (c < 6) ? 0 : 32;    // which neighbor list
            const int g     = tid >> 6;            // 0..7
            #pragma unroll 2
            for (int mm = 0; mm < 8; ++mm) {
                const int m = g * 8 + mm;
                const int4* ip = (const int4*)&idxs[m][lbase];
                float s = 0.f;
                #pragma unroll
                for (int q = 0; q < 8; ++q) {
                    int4 nb = ip[q];
                    s += fea1[nb.x * DIM + kbase + col];
                    s += fea1[nb.y * DIM + kbase + col];
                    s += fea1[nb.z * DIM + kbase + col];
                    s += fea1[nb.w * DIM + kbase + col];
                }
                As[col][m] = s * (1.0f / 32.0f);
            }
        }
        __syncthreads();

        // ---------- GEMM over this K-chunk ----------
        const float* wp = W + (c * KC) * DOUT + j0;
        #pragma unroll 4
        for (int k = 0; k < KC; ++k) {
            float4 w = *(const float4*)(wp + k * DOUT);
            float4 a = *(const float4*)&As[k][m0];
            float av[4] = {a.x, a.y, a.z, a.w};
            #pragma unroll
            for (int i = 0; i < 4; ++i) {
                acc[i][0] += av[i] * w.x;
                acc[i][1] += av[i] * w.y;
                acc[i][2] += av[i] * w.z;
                acc[i][3] += av[i] * w.w;
            }
        }
        __syncthreads();
    }

    // ---------- epilogue: tanh + store ----------
    #pragma unroll
    for (int i = 0; i < 4; ++i) {
        int node = n0 + m0 + i;
        if (node < N_NODES) {
            float4 r;
            r.x = tanhf(acc[i][0]);
            r.y = tanhf(acc[i][1]);
            r.z = tanhf(acc[i][2]);
            r.w = tanhf(acc[i][3]);
            *(float4*)(out + node * DOUT + j0) = r;
        }
    }
}

extern "C" void kernel_launch(void* const* d_in, const int* in_sizes, int n_in,
                              void* d_out, int out_size, void* d_ws, size_t ws_size,
                              hipStream_t stream) {
    const float* fea1 = (const float*)d_in[0];
    const float* fea2 = (const float*)d_in[1];
    const int*   idx1 = (const int*)d_in[2];
    const int*   idx2 = (const int*)d_in[3];
    const float* W    = (const float*)d_in[4];
    float* out = (float*)d_out;

    const int grid = (N_NODES + MT - 1) / MT;   // 782 blocks
    sage_fused<<<grid, 512, 0, stream>>>(fea1, fea2, idx1, idx2, W, out);
}

// Round 3
// 398.160 us; speedup vs baseline: 1.1121x; 1.1121x over previous
//
#include <hip/hip_runtime.h>
#include <math.h>

#define N_NODES 50000
#define KNEI    32
#define DIM     128
#define DOUT    128
#define MT      64      // nodes per block
#define KC      128     // K-chunk: one full source per chunk
#define AS_STRIDE 68    // padded LDS stride

// round-to-nearest-even fp32 -> bf16
static __device__ __forceinline__ unsigned short f2bf(float f) {
    unsigned int u = __float_as_uint(f);
    unsigned int lsb = (u >> 16) & 1u;
    u += 0x7fffu + lsb;
    return (unsigned short)(u >> 16);
}

__global__ __launch_bounds__(256) void convert_bf16(
    const float* __restrict__ src, unsigned short* __restrict__ dst, int n4)
{
    int i = blockIdx.x * blockDim.x + threadIdx.x;
    if (i >= n4) return;
    float4 v = ((const float4*)src)[i];
    ushort4 o;
    o.x = f2bf(v.x); o.y = f2bf(v.y); o.z = f2bf(v.z); o.w = f2bf(v.w);
    ((ushort4*)dst)[i] = o;
}

__global__ __launch_bounds__(256) void sage_fused(
    const float*          __restrict__ fea1,
    const float*          __restrict__ fea2,
    const unsigned short* __restrict__ bf1,   // bf16 copy of fea1
    const int*            __restrict__ idx1,
    const int*            __restrict__ idx2,
    const float*          __restrict__ W,
    float*                __restrict__ out)
{
    __shared__ float As[KC][AS_STRIDE];   // A-tile, transposed: As[k][m]
    __shared__ int   idxs[MT][64];        // [node][0:32]=list1, [32:64]=list2

    const int tid = threadIdx.x;
    const int n0  = blockIdx.x * MT;

    // ---- stage neighbor indices for the 64 nodes of this tile ----
    #pragma unroll
    for (int i = 0; i < 8; ++i) {
        int e  = tid + i * 256;           // 0..2047
        int m  = e >> 5;
        int kk = e & 31;
        int node = n0 + m;
        if (node >= N_NODES) node = N_NODES - 1;   // clamp; store guarded later
        idxs[m][kk]      = idx1[node * KNEI + kk];
        idxs[m][32 + kk] = idx2[node * KNEI + kk];
    }

    float acc[8][4];
    #pragma unroll
    for (int i = 0; i < 8; ++i)
        #pragma unroll
        for (int j = 0; j < 4; ++j) acc[i][j] = 0.f;

    const int j0 = (tid & 31) * 4;        // output column base (0..124)
    const int m0 = (tid >> 5) * 8;        // output row base    (0..56)

    for (int c = 0; c < 4; ++c) {
        // ---------- stage A-tile for this K-chunk ----------
        if (c < 2) {
            // direct features: chunk 0 = fea1, 1 = fea2 (fp32, coalesced float4)
            const float* src = (c == 0) ? fea1 : fea2;
            #pragma unroll
            for (int i = 0; i < 8; ++i) {
                int f  = tid + i * 256;   // 0..2047 float4 slots
                int m  = f >> 5;          // 32 float4 per 128-col row
                int c4 = (f & 31) * 4;
                int node = n0 + m;
                if (node >= N_NODES) node = N_NODES - 1;
                float4 v = *(const float4*)(src + node * DIM + c4);
                As[c4 + 0][m] = v.x;
                As[c4 + 1][m] = v.y;
                As[c4 + 2][m] = v.z;
                As[c4 + 3][m] = v.w;
            }
        } else {
            // neighbor-mean chunks from bf16 copy: chunk 2 = list1, 3 = list2
            const int lbase = (c == 2) ? 0 : 32;
            const int lane  = tid & 63;   // covers cols 2*lane, 2*lane+1
            const int w     = tid >> 6;   // wave id 0..3 -> 16 nodes each
            for (int mm = 0; mm < 16; ++mm) {
                const int m = w * 16 + mm;
                const int* ip = &idxs[m][lbase];
                float s0a = 0.f, s0b = 0.f, s1a = 0.f, s1b = 0.f;
                #pragma unroll
                for (int q = 0; q < 32; q += 2) {
                    int nb0 = ip[q];
                    int nb1 = ip[q + 1];
                    unsigned int u0 = *(const unsigned int*)(bf1 + nb0 * DIM + 2 * lane);
                    unsigned int u1 = *(const unsigned int*)(bf1 + nb1 * DIM + 2 * lane);
                    s0a += __uint_as_float(u0 << 16);
                    s1a += __uint_as_float(u0 & 0xffff0000u);
                    s0b += __uint_as_float(u1 << 16);
                    s1b += __uint_as_float(u1 & 0xffff0000u);
                }
                As[2 * lane + 0][m] = (s0a + s0b) * (1.0f / 32.0f);
                As[2 * lane + 1][m] = (s1a + s1b) * (1.0f / 32.0f);
            }
        }
        __syncthreads();

        // ---------- GEMM over this K-chunk (128 k-steps) ----------
        const float* wp = W + (c * KC) * DOUT + j0;
        #pragma unroll 4
        for (int k = 0; k < KC; ++k) {
            float4 w4 = *(const float4*)(wp + k * DOUT);
            const float4* ap = (const float4*)&As[k][m0];
            float4 a0 = ap[0];
            float4 a1 = ap[1];
            float av[8] = {a0.x, a0.y, a0.z, a0.w, a1.x, a1.y, a1.z, a1.w};
            #pragma unroll
            for (int i = 0; i < 8; ++i) {
                acc[i][0] += av[i] * w4.x;
                acc[i][1] += av[i] * w4.y;
                acc[i][2] += av[i] * w4.z;
                acc[i][3] += av[i] * w4.w;
            }
        }
        __syncthreads();
    }

    // ---------- epilogue: tanh + store ----------
    #pragma unroll
    for (int i = 0; i < 8; ++i) {
        int node = n0 + m0 + i;
        if (node < N_NODES) {
            float4 r;
            r.x = tanhf(acc[i][0]);
            r.y = tanhf(acc[i][1]);
            r.z = tanhf(acc[i][2]);
            r.w = tanhf(acc[i][3]);
            *(float4*)(out + node * DOUT + j0) = r;
        }
    }
}

extern "C" void kernel_launch(void* const* d_in, const int* in_sizes, int n_in,
                              void* d_out, int out_size, void* d_ws, size_t ws_size,
                              hipStream_t stream) {
    const float* fea1 = (const float*)d_in[0];
    const float* fea2 = (const float*)d_in[1];
    const int*   idx1 = (const int*)d_in[2];
    const int*   idx2 = (const int*)d_in[3];
    const float* W    = (const float*)d_in[4];
    float* out = (float*)d_out;
    unsigned short* bf1 = (unsigned short*)d_ws;   // 50000*128*2 B = 12.8 MB

    const int n4 = N_NODES * DIM / 4;              // 1.6M float4s
    convert_bf16<<<(n4 + 255) / 256, 256, 0, stream>>>(fea1, bf1, n4);

    const int grid = (N_NODES + MT - 1) / MT;      // 782 blocks
    sage_fused<<<grid, 256, 0, stream>>>(fea1, fea2, bf1, idx1, idx2, W, out);
}

// Round 4
// 210.905 us; speedup vs baseline: 2.0995x; 1.8879x over previous
//
#include <hip/hip_runtime.h>
#include <math.h>

#define N_NODES 50000
#define KNEI    32
#define DIM     128
#define DOUT    128

typedef __attribute__((ext_vector_type(8))) short short8;
typedef __attribute__((ext_vector_type(4))) float floatx4;

// round-to-nearest-even fp32 -> bf16
static __device__ __forceinline__ unsigned short f2bf(float f) {
    unsigned int u = __float_as_uint(f);
    unsigned int lsb = (u >> 16) & 1u;
    u += 0x7fffu + lsb;
    return (unsigned short)(u >> 16);
}

// ---------------- fast path kernels ----------------

// fea (fp32 [N,128]) -> bf16 into A[N][512] at colBase
__global__ __launch_bounds__(256) void convert_cols(
    const float* __restrict__ src, unsigned short* __restrict__ A, int colBase)
{
    int t = blockIdx.x * 256 + threadIdx.x;        // 0 .. N*32-1
    int node = t >> 5;
    int c4 = (t & 31) * 4;
    float4 v = *(const float4*)(src + node * DIM + c4);
    ushort4 o;
    o.x = f2bf(v.x); o.y = f2bf(v.y); o.z = f2bf(v.z); o.w = f2bf(v.w);
    *(ushort4*)(A + node * 512 + colBase + c4) = o;
}

// W fp32 [512,128] -> Wt bf16 [128][512]
__global__ __launch_bounds__(256) void transpose_w(
    const float* __restrict__ W, unsigned short* __restrict__ Wt)
{
    int t = blockIdx.x * 256 + threadIdx.x;   // 0..65535
    int k = t >> 7, n = t & 127;
    Wt[n * 512 + k] = f2bf(W[t]);
}

// one wave per (node,list): mean of 32 gathered bf16 rows -> A cols 256..511
__global__ __launch_bounds__(256) void aggregate(
    unsigned short* __restrict__ A,
    const int* __restrict__ idx1,
    const int* __restrict__ idx2)
{
    const int tid  = threadIdx.x;
    const int u    = blockIdx.x * 4 + (tid >> 6);   // 0..99999
    const int node = u >> 1;
    const int list = u & 1;
    const int lane = tid & 63;
    const int* ip  = (list ? idx2 : idx1) + node * KNEI;
    int nb = ip[lane & 31];

    float s0 = 0.f, s1 = 0.f;
    #pragma unroll
    for (int b = 0; b < 2; ++b) {
        unsigned int r[16];
        #pragma unroll
        for (int q = 0; q < 16; ++q) {
            int nq = __shfl(nb, b * 16 + q, 64);
            r[q] = *(const unsigned int*)(A + nq * 512 + 2 * lane);
        }
        #pragma unroll
        for (int q = 0; q < 16; ++q) {
            s0 += __uint_as_float(r[q] << 16);
            s1 += __uint_as_float(r[q] & 0xffff0000u);
        }
    }
    s0 *= (1.f / 32.f);
    s1 *= (1.f / 32.f);
    unsigned int o = (unsigned int)f2bf(s0) | ((unsigned int)f2bf(s1) << 16);
    *(unsigned int*)(A + node * 512 + 256 + list * 128 + 2 * lane) = o;
}

// C = tanh(A[50000,512] @ Wt^T), bf16 MFMA, fp32 accum
__global__ __launch_bounds__(256) void gemm_tanh(
    const unsigned short* __restrict__ A,
    const unsigned short* __restrict__ Wt,
    float* __restrict__ out)
{
    __shared__ unsigned short As[64][72];    // 9216 B  (stride 144 B, 16B-aligned rows)
    __shared__ unsigned short Bs[128][72];   // 18432 B

    const int tid  = threadIdx.x;
    const int w    = tid >> 6;
    const int lane = tid & 63;
    const int m0   = blockIdx.x * 64;
    const int wm   = (w & 1) * 32;
    const int wn   = (w >> 1) * 64;
    const int lm   = lane & 15;
    const int lk   = (lane >> 4) * 8;

    floatx4 acc[2][4];
    #pragma unroll
    for (int i = 0; i < 2; ++i)
        #pragma unroll
        for (int j = 0; j < 4; ++j)
            acc[i][j] = (floatx4){0.f, 0.f, 0.f, 0.f};

    for (int kb = 0; kb < 512; kb += 64) {
        // stage A tile 64x64 bf16 (512 16B slots, 2/thread)
        #pragma unroll
        for (int i = 0; i < 2; ++i) {
            int slot = tid + i * 256;
            int row = slot >> 3, o = (slot & 7) * 8;
            int node = m0 + row;
            if (node >= N_NODES) node = N_NODES - 1;
            *(int4*)&As[row][o] = *(const int4*)(A + node * 512 + kb + o);
        }
        // stage Wt tile 128x64 bf16 (1024 slots, 4/thread)
        #pragma unroll
        for (int i = 0; i < 4; ++i) {
            int slot = tid + i * 256;
            int row = slot >> 3, o = (slot & 7) * 8;
            *(int4*)&Bs[row][o] = *(const int4*)(Wt + row * 512 + kb + o);
        }
        __syncthreads();

        #pragma unroll
        for (int ks = 0; ks < 64; ks += 32) {
            short8 af[2], bf_[4];
            #pragma unroll
            for (int im = 0; im < 2; ++im)
                af[im] = *(const short8*)&As[wm + im * 16 + lm][ks + lk];
            #pragma unroll
            for (int in = 0; in < 4; ++in)
                bf_[in] = *(const short8*)&Bs[wn + in * 16 + lm][ks + lk];
            #pragma unroll
            for (int im = 0; im < 2; ++im)
                #pragma unroll
                for (int in = 0; in < 4; ++in)
                    acc[im][in] = __builtin_amdgcn_mfma_f32_16x16x32_bf16(
                        af[im], bf_[in], acc[im][in], 0, 0, 0);
        }
        __syncthreads();
    }

    // epilogue: tanh + scattered fp32 stores (C/D: col=lane&15, row=(lane>>4)*4+reg)
    #pragma unroll
    for (int im = 0; im < 2; ++im) {
        int rbase = m0 + wm + im * 16 + (lane >> 4) * 4;
        #pragma unroll
        for (int in = 0; in < 4; ++in) {
            int col = wn + in * 16 + lm;
            #pragma unroll
            for (int r = 0; r < 4; ++r) {
                int node = rbase + r;
                if (node < N_NODES)
                    out[node * DOUT + col] = tanhf(acc[im][in][r]);
            }
        }
    }
}

// ---------------- fallback (ws too small): round-1 fused fp32 ----------------
#define MT      64
#define KC      64
#define AS_STRIDE 68

__global__ __launch_bounds__(256) void sage_fused_fb(
    const float* __restrict__ fea1, const float* __restrict__ fea2,
    const int* __restrict__ idx1, const int* __restrict__ idx2,
    const float* __restrict__ W, float* __restrict__ out)
{
    __shared__ float As[KC][AS_STRIDE];
    __shared__ int   idxs[MT][64];
    const int tid = threadIdx.x;
    const int n0  = blockIdx.x * MT;
    #pragma unroll
    for (int i = 0; i < 8; ++i) {
        int e = tid + i * 256, m = e >> 5, kk = e & 31;
        int node = n0 + m; if (node >= N_NODES) node = N_NODES - 1;
        idxs[m][kk]      = idx1[node * KNEI + kk];
        idxs[m][32 + kk] = idx2[node * KNEI + kk];
    }
    float acc[8][4];
    #pragma unroll
    for (int i = 0; i < 8; ++i)
        #pragma unroll
        for (int j = 0; j < 4; ++j) acc[i][j] = 0.f;
    const int j0 = (tid & 31) * 4;
    const int m0 = (tid >> 5) * 8;
    for (int c = 0; c < 8; ++c) {
        if (c < 4) {
            const float* src = (c < 2) ? fea1 : fea2;
            const int cbase = (c & 1) * 64;
            #pragma unroll
            for (int i = 0; i < 4; ++i) {
                int f = tid + i * 256, m = f >> 4, c4 = (f & 15) * 4;
                int node = n0 + m; if (node >= N_NODES) node = N_NODES - 1;
                float4 v = *(const float4*)(src + node * DIM + cbase + c4);
                As[c4 + 0][m] = v.x; As[c4 + 1][m] = v.y;
                As[c4 + 2][m] = v.z; As[c4 + 3][m] = v.w;
            }
        } else {
            const int col = tid & 63, kbase = (c & 1) * 64;
            const int lbase = (c < 6) ? 0 : 32, g = tid >> 6;
            for (int mm = 0; mm < 16; ++mm) {
                const int m = g * 16 + mm;
                const int4* ip = (const int4*)&idxs[m][lbase];
                float s = 0.f;
                #pragma unroll
                for (int q = 0; q < 8; ++q) {
                    int4 nb = ip[q];
                    s += fea1[nb.x * DIM + kbase + col];
                    s += fea1[nb.y * DIM + kbase + col];
                    s += fea1[nb.z * DIM + kbase + col];
                    s += fea1[nb.w * DIM + kbase + col];
                }
                As[col][m] = s * (1.0f / 32.0f);
            }
        }
        __syncthreads();
        const float* wp = W + (c * KC) * DOUT + j0;
        #pragma unroll 4
        for (int k = 0; k < KC; ++k) {
            float4 w4 = *(const float4*)(wp + k * DOUT);
            const float4* ap = (const float4*)&As[k][m0];
            float4 a0 = ap[0]; float4 a1 = ap[1];
            float av[8] = {a0.x, a0.y, a0.z, a0.w, a1.x, a1.y, a1.z, a1.w};
            #pragma unroll
            for (int i = 0; i < 8; ++i) {
                acc[i][0] += av[i] * w4.x; acc[i][1] += av[i] * w4.y;
                acc[i][2] += av[i] * w4.z; acc[i][3] += av[i] * w4.w;
            }
        }
        __syncthreads();
    }
    #pragma unroll
    for (int i = 0; i < 8; ++i) {
        int node = n0 + m0 + i;
        if (node < N_NODES) {
            float4 r;
            r.x = tanhf(acc[i][0]); r.y = tanhf(acc[i][1]);
            r.z = tanhf(acc[i][2]); r.w = tanhf(acc[i][3]);
            *(float4*)(out + node * DOUT + j0) = r;
        }
    }
}

extern "C" void kernel_launch(void* const* d_in, const int* in_sizes, int n_in,
                              void* d_out, int out_size, void* d_ws, size_t ws_size,
                              hipStream_t stream) {
    const float* fea1 = (const float*)d_in[0];
    const float* fea2 = (const float*)d_in[1];
    const int*   idx1 = (const int*)d_in[2];
    const int*   idx2 = (const int*)d_in[3];
    const float* W    = (const float*)d_in[4];
    float* out = (float*)d_out;

    const size_t A_BYTES  = (size_t)N_NODES * 512 * 2;        // 51,200,000
    const size_t WT_BYTES = (size_t)512 * 128 * 2;            // 131,072

    if (ws_size >= A_BYTES + WT_BYTES) {
        unsigned short* A  = (unsigned short*)d_ws;
        unsigned short* Wt = (unsigned short*)((char*)d_ws + A_BYTES);

        convert_cols<<<N_NODES * 32 / 256, 256, 0, stream>>>(fea1, A, 0);
        convert_cols<<<N_NODES * 32 / 256, 256, 0, stream>>>(fea2, A, 128);
        transpose_w<<<512 * 128 / 256, 256, 0, stream>>>(W, Wt);
        aggregate<<<2 * N_NODES / 4, 256, 0, stream>>>(A, idx1, idx2);
        gemm_tanh<<<(N_NODES + 63) / 64, 256, 0, stream>>>(A, Wt, out);
    } else {
        const int grid = (N_NODES + MT - 1) / MT;
        sage_fused_fb<<<grid, 256, 0, stream>>>(fea1, fea2, idx1, idx2, W, out);
    }
}